// Round 10
// baseline (28.389 us; speedup 1.0000x reference)
//
#include <hip/hip_runtime.h>

// Gaussian-splat heatmap as a per-image MFMA GEMM — two-pass with LDS-staged
// streaming stores (write-amplification fix).
//   heat[y][x] = sum_p Rmat[y][p] * CmatT[x][p]   (M=N=200 padded to 224, K=64)
//   Rmat[y][p]  = k1n[y-ys_p] if 0<=y-ys_p<ky_p else 0  (top-left-slice quirk)
//   CmatT[x][p] = k1n[x-xs_p] if 0<=x-xs_p<kx_p else 0
// bf16 LDS rows of 128 B, XOR-swizzled byte ^= ((row&7)<<4) (G4/T2).
// mfma_f32_32x32x16_bf16; A-frag: lane l -> row l&31, k=8*(l>>5)+j;
// C/D: col=lane&31 (=N=x), row=(reg&3)+8*(reg>>2)+4*(lane>>5) (=M=y)  [m74/m101]
//
// vs r6 (24.9us) / r9 (27.6us): r5's counters showed 2.9x HBM write
// amplification for scattered 16B-chunk stores; r6's 128B segments are also
// not line-aligned (row stride 800B). Here pass 2 runs in 14 phases: per
// 32-row tile, waves compute one 32x32 tile each (B-frag Cm@wv loaded once,
// A-frag Rm@ty per phase), dump scaled f32 to a strip[16][224] LDS buffer,
// then all 448 threads stream the strip as CONTIGUOUS float4 bursts — each
// 16-row strip of an image is one contiguous 128B-aligned 12.8KB span, so
// every HBM line is fully written. LDS 71.7KB keeps 2 blocks/CU (R7/R8: 
// co-residency beats everything). Same per-element k-order -> bit-identical.

#define NT 64
#define TDIM 224
#define NTL 7
#define BLK 448

typedef short bf16x8 __attribute__((ext_vector_type(8)));
typedef float f32x16 __attribute__((ext_vector_type(16)));

// f32 -> bf16 round-to-nearest-even
static __device__ inline unsigned f2bf(float f) {
    unsigned int u = __float_as_uint(f);
    u = (u + 0x7FFFu + ((u >> 16) & 1u)) >> 16;
    return u & 0xFFFFu;
}

struct __align__(16) SMem {
    unsigned short Rm[TDIM][64];   // 28,672 B, swizzled (rows = y)
    unsigned short Cm[TDIM][64];   // 28,672 B, swizzled (rows = x)
    float strip[16][TDIM];         // 14,336 B store-staging strip
    float wmax[NTL];
};

__global__ __launch_bounds__(BLK) void heatmap_kernel(const float* __restrict__ x_t,
                                                      float* __restrict__ out) {
    __shared__ SMem s;
    const int tid  = threadIdx.x;
    const int lane = tid & 63;
    const int wv   = tid >> 6;      // 0..6
    const int b    = blockIdx.x;

    // 1/sum of the 37-tap gaussian (fully unrolled -> constant-folded)
    float ssum = 0.0f;
    #pragma unroll
    for (int i = 0; i < 37; ++i) {
        float r = (float)(i - 18);
        ssum += expf(-(r * r) * (1.0f / 18.0f));   // sigma=3 -> 2*sigma^2=18
    }
    const float invs = 1.0f / ssum;

    // --- build Rm + Cm: thread = (point-quad q4, row-group rg), b64 writes ---
    {
        const int q4 = tid & 15;      // points 4q4..4q4+3
        const int rg = tid >> 4;      // 0..27; rows rg + 28*i, i<8
        const float4 p01 = *(const float4*)(x_t + (size_t)b * 128 + 8 * q4);
        const float4 p23 = *(const float4*)(x_t + (size_t)b * 128 + 8 * q4 + 4);
        float px[4] = {p01.x, p01.z, p23.x, p23.z};
        float py[4] = {p01.y, p01.w, p23.y, p23.w};
        int xs[4], ys[4], kx[4], ky[4];
        #pragma unroll
        for (int k = 0; k < 4; ++k) {   // replicates reference exactly
            bool valid = (px[k] == px[k]) && (py[k] == py[k]);
            int xp = (int)(px[k] * 2.0f);          // trunc == astype(int32), x>=0
            int yp = 200 - (int)(py[k] * 2.0f);
            xs[k] = min(max(xp - 18, 0), 164);
            ys[k] = min(max(yp - 18, 0), 164);
            kx[k] = valid ? (min(max(xp + 18, 0), 200) - xs[k]) : 0;   // <= 36
            ky[k] = valid ? (min(max(yp + 18, 0), 200) - ys[k]) : 0;
        }
        #pragma unroll
        for (int i = 0; i < 8; ++i) {
            const int row = rg + 28 * i;           // covers 0..223
            const int off = (8 * q4) ^ ((row & 7) << 4);
            unsigned rv[4], cv[4];
            #pragma unroll
            for (int k = 0; k < 4; ++k) {
                int d = row - ys[k];
                float fd = (float)(d - 18);
                float v = expf(-(fd * fd) * (1.0f / 18.0f)) * invs;
                rv[k] = ((unsigned)d < (unsigned)ky[k]) ? f2bf(v) : 0u;
                int e = row - xs[k];
                float fe = (float)(e - 18);
                float w = expf(-(fe * fe) * (1.0f / 18.0f)) * invs;
                cv[k] = ((unsigned)e < (unsigned)kx[k]) ? f2bf(w) : 0u;
            }
            uint2 R = {rv[0] | (rv[1] << 16), rv[2] | (rv[3] << 16)};
            *(uint2*)((char*)s.Rm + row * 128 + off) = R;
            uint2 C = {cv[0] | (cv[1] << 16), cv[2] | (cv[3] << 16)};
            *(uint2*)((char*)s.Cm + row * 128 + off) = C;
        }
    }
    __syncthreads();

    const int swl = (lane & 7) << 4;    // swizzle term (rows = t*32+(lane&31))

    // --- pass 1: max; wave owns y-tile wv (A=Rm@wv fixed), loops x-tiles ---
    float gmax = 0.0f;
    {
        bf16x8 Af[4];
        const char* ab = (const char*)s.Rm + (wv * 32 + (lane & 31)) * 128;
        #pragma unroll
        for (int m = 0; m < 4; ++m)
            Af[m] = *(const bf16x8*)(ab + ((16 * (2 * m + (lane >> 5))) ^ swl));
        for (int tx = 0; tx < NTL; ++tx) {
            const char* bb = (const char*)s.Cm + (tx * 32 + (lane & 31)) * 128;
            f32x16 acc;
            #pragma unroll
            for (int r = 0; r < 16; ++r) acc[r] = 0.0f;
            #pragma unroll
            for (int m = 0; m < 4; ++m) {
                bf16x8 Bf = *(const bf16x8*)(bb + ((16 * (2 * m + (lane >> 5))) ^ swl));
                acc = __builtin_amdgcn_mfma_f32_32x32x16_bf16(Af[m], Bf, acc, 0, 0, 0);
            }
            #pragma unroll
            for (int r = 0; r < 16; ++r) gmax = fmaxf(gmax, acc[r]);
        }
    }
    #pragma unroll
    for (int off = 32; off > 0; off >>= 1) gmax = fmaxf(gmax, __shfl_xor(gmax, off));
    if (lane == 0) s.wmax[wv] = gmax;
    __syncthreads();
    float mm = s.wmax[0];
    #pragma unroll
    for (int w = 1; w < NTL; ++w) mm = fmaxf(mm, s.wmax[w]);
    const float scale = 1.0f / (mm + 1e-10f);

    // --- pass 2: wave owns x-tile wv (B=Cm@wv fixed, loaded ONCE); per y-tile
    //     ty compute 32x32, dump scaled halves to strip, stream contiguously ---
    bf16x8 Bf2[4];
    {
        const char* cb = (const char*)s.Cm + (wv * 32 + (lane & 31)) * 128;
        #pragma unroll
        for (int m = 0; m < 4; ++m)
            Bf2[m] = *(const bf16x8*)(cb + ((16 * (2 * m + (lane >> 5))) ^ swl));
    }
    float* ob = out + (size_t)b * (200 * 200);
    for (int ty = 0; ty < NTL; ++ty) {
        const char* ab = (const char*)s.Rm + (ty * 32 + (lane & 31)) * 128;
        f32x16 acc;
        #pragma unroll
        for (int r = 0; r < 16; ++r) acc[r] = 0.0f;
        #pragma unroll
        for (int m = 0; m < 4; ++m) {
            bf16x8 Af = *(const bf16x8*)(ab + ((16 * (2 * m + (lane >> 5))) ^ swl));
            acc = __builtin_amdgcn_mfma_f32_32x32x16_bf16(Af, Bf2[m], acc, 0, 0, 0);
        }
        #pragma unroll
        for (int h = 0; h < 2; ++h) {
            const int ybase = ty * 32 + 16 * h;
            const int nrow  = min(16, 200 - ybase);   // 16; 8 @ty=6,h=0; <=0 @ty=6,h=1
            if (nrow <= 0) continue;                  // uniform across block
            __syncthreads();                          // strip free (prev stream done)
            #pragma unroll
            for (int rr = 0; rr < 8; ++rr) {
                const int r  = rr + 8 * h;
                const int yl = (r & 3) + 8 * ((r >> 2) & 1) + 4 * (lane >> 5); // 0..15
                s.strip[yl][32 * wv + (lane & 31)] = acc[r] * scale;
            }
            __syncthreads();                          // dump visible
            // contiguous, 128B-aligned 12.8KB (or 6.4KB) span: full-line writes
            for (int id = tid; id < nrow * 50; id += BLK) {
                const int yl = id / 50;
                const int x4 = id - 50 * yl;
                float4 v = *(const float4*)&s.strip[yl][4 * x4];
                *(float4*)(ob + (size_t)(ybase + yl) * 200 + 4 * x4) = v;
            }
        }
    }
}

extern "C" void kernel_launch(void* const* d_in, const int* in_sizes, int n_in,
                              void* d_out, int out_size, void* d_ws, size_t ws_size,
                              hipStream_t stream) {
    const float* x_t = (const float*)d_in[0];
    float* out = (float*)d_out;
    const int B = in_sizes[0] / (NT * 2);   // 512
    heatmap_kernel<<<B, BLK, 0, stream>>>(x_t, out);
}

// Round 11
// 24.260 us; speedup vs baseline: 1.1702x; 1.1702x over previous
//
#include <hip/hip_runtime.h>

// Gaussian-splat heatmap as a per-image MFMA GEMM — R6 structure with a
// zero-fill + sparse-write build (single-variable change vs R6, 24.9us).
//   heat[y][x] = sum_p Rmat[y][p] * CmatT[x][p]   (M=N=200 padded to 224, K=64)
//   Rmat[y][p]  = k1n[y-ys_p] if 0<=y-ys_p<ky_p else 0  (top-left-slice quirk)
//   CmatT[x][p] = k1n[x-xs_p] if 0<=x-xs_p<kx_p else 0
// bf16 LDS rows of 128 B, XOR-swizzled byte ^= ((row&7)<<4) (G4/T2).
// mfma_f32_32x32x16_bf16; A-frag: lane l -> row l&31, k=8*(l>>5)+j;
// C/D: col=lane&31, row=(reg&3)+8*(reg>>2)+4*(lane>>5)   [m74/m101]
//
// Build rationale: matrices are ~84% zeros (each point spans <=36 of 224 rows).
// R6 built densely: ~96 LDS ops/thread (~5us serialized LDS-pipe per CU).
// Here: b128 zero-fill (7 ops/thread) + f32 k1n table (broadcast/distinct-bank
// reads, conflict-free) + one ds_write_b16 per NONZERO entry (9/thread).
// Same bf16 values, same layout, same passes -> bit-identical output to R6.

#define NT 64
#define TDIM 224
#define NTL 7
#define BLK 512

typedef short bf16x8 __attribute__((ext_vector_type(8)));
typedef float f32x16 __attribute__((ext_vector_type(16)));

// f32 -> bf16 round-to-nearest-even
static __device__ inline unsigned short f2bf(float f) {
    unsigned int u = __float_as_uint(f);
    u = (u + 0x7FFFu + ((u >> 16) & 1u)) >> 16;
    return (unsigned short)u;
}

struct __align__(16) SMem {
    unsigned short Rm[TDIM][64];   // 28,672 B, swizzled (rows = y)
    unsigned short Cm[TDIM][64];   // 28,672 B, swizzled (rows = x)  (contiguous with Rm)
    float k1f[37];                 // f32 normalized 1-D gaussian
    float wmax[NTL];
};

__global__ __launch_bounds__(BLK) void heatmap_kernel(const float* __restrict__ x_t,
                                                      float* __restrict__ out) {
    __shared__ SMem s;
    const int tid  = threadIdx.x;
    const int lane = tid & 63;
    const int wv   = tid >> 6;      // 0..7 (wave 7 idles in compute, helps build)
    const int b    = blockIdx.x;

    // --- (1) zero-fill Rm+Cm with b128 writes: 57,344 B = 3584 x 16 B ---
    {
        uint4 z = {0u, 0u, 0u, 0u};
        uint4* base = (uint4*)s.Rm;
        #pragma unroll
        for (int i = 0; i < 7; ++i) base[tid + BLK * i] = z;
    }
    // --- (2) f32 normalized 1-D gaussian table ---
    if (tid < 37) {
        float sum = 0.0f, mine = 0.0f;
        #pragma unroll
        for (int i = 0; i < 37; ++i) {
            float r = (float)(i - 18);
            float v = expf(-(r * r) * (1.0f / 18.0f));   // sigma=3 -> 2*sigma^2=18
            sum += v;
            if (i == tid) mine = v;
        }
        s.k1f[tid] = mine / sum;
    }
    __syncthreads();

    // --- (3) sparse build: task = (point p, matrix R/C), 4 threads x 9 rows ---
    {
        const int p   = (tid >> 2) & 63;    // point
        const int isC = tid >> 8;           // 0: Rm (rows=y), 1: Cm (rows=x)
        const int j   = tid & 3;            // 9-row slice
        const float2 xy = *(const float2*)(x_t + (size_t)b * 128 + 2 * p);
        // replicates reference exactly
        const bool valid = (xy.x == xy.x) && (xy.y == xy.y);
        const int xp = (int)(xy.x * 2.0f);            // trunc == astype(int32), x>=0
        const int yp = 200 - (int)(xy.y * 2.0f);
        const int xs = min(max(xp - 18, 0), 164);
        const int ys = min(max(yp - 18, 0), 164);
        const int kx = valid ? (min(max(xp + 18, 0), 200) - xs) : 0;   // <= 36
        const int ky = valid ? (min(max(yp + 18, 0), 200) - ys) : 0;
        const int start = isC ? xs : ys;
        const int len   = isC ? kx : ky;
        char* dst = isC ? (char*)s.Cm : (char*)s.Rm;
        #pragma unroll
        for (int i = 0; i < 9; ++i) {
            const int rel = j * 9 + i;                // 0..35
            if (rel < len) {
                const int row = start + rel;          // <= 199
                const int off = (2 * p) ^ ((row & 7) << 4);
                *(unsigned short*)(dst + row * 128 + off) = f2bf(s.k1f[rel]);
            }
        }
    }
    __syncthreads();

    const int swl = (lane & 7) << 4;    // swizzle term (rows = t*32+(lane&31))

    // --- A fragments for this wave's y-tile ---
    bf16x8 A[4];
    if (wv < NTL) {
        const char* ab = (const char*)s.Rm + (wv * 32 + (lane & 31)) * 128;
        #pragma unroll
        for (int m = 0; m < 4; ++m)
            A[m] = *(const bf16x8*)(ab + ((16 * (2 * m + (lane >> 5))) ^ swl));
    }

    // --- pass 1: max ---
    float gmax = 0.0f;
    if (wv < NTL) {
        for (int tx = 0; tx < NTL; ++tx) {
            const char* bb = (const char*)s.Cm + (tx * 32 + (lane & 31)) * 128;
            f32x16 acc;
            #pragma unroll
            for (int r = 0; r < 16; ++r) acc[r] = 0.0f;
            #pragma unroll
            for (int m = 0; m < 4; ++m) {
                bf16x8 B = *(const bf16x8*)(bb + ((16 * (2 * m + (lane >> 5))) ^ swl));
                acc = __builtin_amdgcn_mfma_f32_32x32x16_bf16(A[m], B, acc, 0, 0, 0);
            }
            #pragma unroll
            for (int r = 0; r < 16; ++r) gmax = fmaxf(gmax, acc[r]);
        }
    }
    #pragma unroll
    for (int off = 32; off > 0; off >>= 1) gmax = fmaxf(gmax, __shfl_xor(gmax, off));
    if (wv < NTL && lane == 0) s.wmax[wv] = gmax;
    __syncthreads();
    float mm = s.wmax[0];
    #pragma unroll
    for (int w = 1; w < NTL; ++w) mm = fmaxf(mm, s.wmax[w]);
    const float scale = 1.0f / (mm + 1e-10f);

    // --- pass 2: recompute, normalize, store (R6 scattered-dword pattern) ---
    if (wv < NTL) {
        float* ob = out + (size_t)b * (200 * 200);
        const int colbase = lane & 31;
        const int rowoff  = wv * 32 + 4 * (lane >> 5);
        for (int tx = 0; tx < NTL; ++tx) {
            const char* bb = (const char*)s.Cm + (tx * 32 + (lane & 31)) * 128;
            f32x16 acc;
            #pragma unroll
            for (int r = 0; r < 16; ++r) acc[r] = 0.0f;
            #pragma unroll
            for (int m = 0; m < 4; ++m) {
                bf16x8 B = *(const bf16x8*)(bb + ((16 * (2 * m + (lane >> 5))) ^ swl));
                acc = __builtin_amdgcn_mfma_f32_32x32x16_bf16(A[m], B, acc, 0, 0, 0);
            }
            const int gcol = tx * 32 + colbase;
            #pragma unroll
            for (int r = 0; r < 16; ++r) {
                int grow = rowoff + (r & 3) + 8 * (r >> 2);
                if (grow < 200 && gcol < 200)
                    ob[grow * 200 + gcol] = acc[r] * scale;
            }
        }
    }
}

extern "C" void kernel_launch(void* const* d_in, const int* in_sizes, int n_in,
                              void* d_out, int out_size, void* d_ws, size_t ws_size,
                              hipStream_t stream) {
    const float* x_t = (const float*)d_in[0];
    float* out = (float*)d_out;
    const int B = in_sizes[0] / (NT * 2);   // 512
    heatmap_kernel<<<B, BLK, 0, stream>>>(x_t, out);
}